// Round 1
// baseline (1891.385 us; speedup 1.0000x reference)
//
#include <hip/hip_runtime.h>

#define T   32      // rows per workgroup
#define LDX 132     // padded LDS row stride (floats)
#define NTH 512     // threads per workgroup: 16 threads per row, 8 cols each

// per-row scalar slots
enum { SF0 = 0, SF1, SO0, SO1, SO2, SO3, SM00, SM01, SM11, SP0, SP1,
       SV0, SV1, SV2, SDP0, SDP1, SM_N };

__device__ __forceinline__ float tanh_fast(float x) {
    // tanh(x) = 1 - 2/(exp(2x)+1); robust at +/-inf, ~1e-7 rel err
    float e = __expf(2.0f * x);
    return 1.0f - 2.0f / (e + 1.0f);
}

__device__ __forceinline__ float red16(float v) {
    // sum across the 16 lanes of a row-group (lanes are contiguous, 16-aligned)
    v += __shfl_xor(v, 1);
    v += __shfl_xor(v, 2);
    v += __shfl_xor(v, 4);
    v += __shfl_xor(v, 8);
    return v;
}

// out[j] = epi(sum_i in_row[i] * W[i*128 + j]) for j in [j0, j0+8)
template <class EPI>
__device__ __forceinline__ void mv128_fwd(const float* __restrict__ Wg,
                                          const float* in_row, int j0, EPI&& epi) {
    float acc[8];
#pragma unroll
    for (int jj = 0; jj < 8; ++jj) acc[jj] = 0.f;
    for (int i = 0; i < 128; i += 4) {
        float4 av = *(const float4*)(in_row + i);
#pragma unroll
        for (int s = 0; s < 4; ++s) {
            float a = (s == 0) ? av.x : (s == 1) ? av.y : (s == 2) ? av.z : av.w;
            const float4* wp = (const float4*)(Wg + (size_t)(i + s) * 128 + j0);
            float4 w0 = wp[0], w1 = wp[1];
            acc[0] += a * w0.x; acc[1] += a * w0.y; acc[2] += a * w0.z; acc[3] += a * w0.w;
            acc[4] += a * w1.x; acc[5] += a * w1.y; acc[6] += a * w1.z; acc[7] += a * w1.w;
        }
    }
#pragma unroll
    for (int jj = 0; jj < 8; ++jj) epi(jj, acc[jj]);
}

// out[j] = epi(sum_k W[j*128 + k] * in_row[k])  (row-of-W reduction, for the h backward pass)
template <class EPI>
__device__ __forceinline__ void mv128_bwd(const float* __restrict__ Wg,
                                          const float* in_row, int j0, EPI&& epi) {
    float acc[8];
#pragma unroll
    for (int jj = 0; jj < 8; ++jj) acc[jj] = 0.f;
    for (int k = 0; k < 128; k += 4) {
        float4 tv = *(const float4*)(in_row + k);
#pragma unroll
        for (int jj = 0; jj < 8; ++jj) {
            float4 w = *(const float4*)(Wg + (size_t)(j0 + jj) * 128 + k);
            acc[jj] += tv.x * w.x + tv.y * w.y + tv.z * w.z + tv.w * w.w;
        }
    }
#pragma unroll
    for (int jj = 0; jj < 8; ++jj) epi(jj, acc[jj]);
}

// small-K (3 or 5) input layer
template <int K, class EPI>
__device__ __forceinline__ void mvK_fwd(const float* __restrict__ Wg,
                                        const float* in, int j0, EPI&& epi) {
    float acc[8];
#pragma unroll
    for (int jj = 0; jj < 8; ++jj) acc[jj] = 0.f;
#pragma unroll
    for (int i = 0; i < K; ++i) {
        float a = in[i];
        const float4* wp = (const float4*)(Wg + (size_t)i * 128 + j0);
        float4 w0 = wp[0], w1 = wp[1];
        acc[0] += a * w0.x; acc[1] += a * w0.y; acc[2] += a * w0.z; acc[3] += a * w0.w;
        acc[4] += a * w1.x; acc[5] += a * w1.y; acc[6] += a * w1.z; acc[7] += a * w1.w;
    }
#pragma unroll
    for (int jj = 0; jj < 8; ++jj) epi(jj, acc[jj]);
}

__global__ __launch_bounds__(NTH)
void symoden_kernel(const float* __restrict__ y,
                    const float* __restrict__ hW1, const float* __restrict__ hb1,
                    const float* __restrict__ hW2, const float* __restrict__ hb2,
                    const float* __restrict__ hW3,
                    const float* __restrict__ mW1, const float* __restrict__ mb1,
                    const float* __restrict__ mW2, const float* __restrict__ mb2,
                    const float* __restrict__ mW3, const float* __restrict__ mb3,
                    const float* __restrict__ gW1, const float* __restrict__ gb1,
                    const float* __restrict__ gW2, const float* __restrict__ gb2,
                    const float* __restrict__ gW3, const float* __restrict__ gb3,
                    float* __restrict__ out) {
    __shared__ __align__(16) float Xb[T * LDX];   // g h1 -> m h1 -> c1m
    __shared__ __align__(16) float Yb[T * LDX];   // g h2 -> m h2 -> c2m
    __shared__ __align__(16) float Zb[T * LDX];   // h h1 -> s -> u1
    __shared__ __align__(16) float Ub[T * LDX];   // h t  -> u2
    __shared__ float ytile[T * 6];
    __shared__ float sm[T][SM_N];
    __shared__ float outtile[T * 6];

    const int tid = threadIdx.x;
    const int r   = tid >> 4;     // row within tile (16 threads per row)
    const int jg  = tid & 15;
    const int j0  = jg * 8;
    const int rowbase = blockIdx.x * T;

    // P0: load y tile (T*6 = 192 contiguous floats)
    if (tid < T * 6) ytile[tid] = y[(size_t)rowbase * 6 + tid];
    __syncthreads();

    const float q0 = ytile[r * 6 + 0];
    const float q1 = ytile[r * 6 + 1];   // cos_q
    const float q2 = ytile[r * 6 + 2];   // sin_q

    float* Xrow = &Xb[r * LDX];
    float* Yrow = &Yb[r * LDX];
    float* Zrow = &Zb[r * LDX];
    float* Urow = &Ub[r * LDX];

    // ---- g-net ----
    // P1: g L1 -> X
    {
        float in3[3] = {q0, q1, q2};
        mvK_fwd<3>(gW1, in3, j0, [&](int jj, float a) {
            Xrow[j0 + jj] = tanh_fast(a + gb1[j0 + jj]);
        });
    }
    __syncthreads();
    // P2: g L2 -> Y
    mv128_fwd(gW2, Xrow, j0, [&](int jj, float a) {
        Yrow[j0 + jj] = tanh_fast(a + gb2[j0 + jj]);
    });
    __syncthreads();
    // P3: g L3 -> F = (Y @ gW3 + gb3) * u   (own-element partials, shuffle reduce)
    {
        float c0 = 0.f, c1 = 0.f;
#pragma unroll
        for (int kk = 0; kk < 8; ++kk) {
            float v = Yrow[j0 + kk];
            c0 += v * gW3[(j0 + kk) * 2 + 0];
            c1 += v * gW3[(j0 + kk) * 2 + 1];
        }
        c0 = red16(c0);
        c1 = red16(c1);
        if (jg == 0) {
            float uu = ytile[r * 6 + 5];
            sm[r][SF0] = (c0 + gb3[0]) * uu;
            sm[r][SF1] = (c1 + gb3[1]) * uu;
        }
    }

    // ---- m-net forward ----
    // P4: m L1 -> X (X free after P2's barrier)
    {
        float in3[3] = {q0, q1, q2};
        mvK_fwd<3>(mW1, in3, j0, [&](int jj, float a) {
            Xrow[j0 + jj] = tanh_fast(a + mb1[j0 + jj]);
        });
    }
    __syncthreads();
    // P5: m L2 -> Y
    mv128_fwd(mW2, Xrow, j0, [&](int jj, float a) {
        Yrow[j0 + jj] = tanh_fast(a + mb2[j0 + jj]);
    });
    __syncthreads();
    // P6: m L3 -> o (A matrix), M = A A^T + I, p = inv(M) @ xq_dot; X->1-X^2, Y->1-Y^2
    {
        float c[4] = {0.f, 0.f, 0.f, 0.f};
#pragma unroll
        for (int kk = 0; kk < 8; ++kk) {
            float v = Yrow[j0 + kk];
            const float4 w = *(const float4*)(mW3 + (size_t)(j0 + kk) * 4);
            c[0] += v * w.x; c[1] += v * w.y; c[2] += v * w.z; c[3] += v * w.w;
        }
#pragma unroll
        for (int cc = 0; cc < 4; ++cc) c[cc] = red16(c[cc]);
        if (jg == 0) {
            float o0 = c[0] + mb3[0], o1 = c[1] + mb3[1];
            float o2 = c[2] + mb3[2], o3 = c[3] + mb3[3];
            float M00 = 1.f + o0 * o0 + o1 * o1;
            float M01 = o0 * o2 + o1 * o3;
            float M11 = 1.f + o2 * o2 + o3 * o3;
            float det = M00 * M11 - M01 * M01;
            float x0 = ytile[r * 6 + 3], x1 = ytile[r * 6 + 4];
            float inv = 1.f / det;
            sm[r][SO0] = o0; sm[r][SO1] = o1; sm[r][SO2] = o2; sm[r][SO3] = o3;
            sm[r][SM00] = M00; sm[r][SM01] = M01; sm[r][SM11] = M11;
            sm[r][SP0] = (M11 * x0 - M01 * x1) * inv;
            sm[r][SP1] = (M00 * x1 - M01 * x0) * inv;
        }
        // in-place: X -> c1 = 1-h1m^2, Y -> c2 = 1-h2m^2 (own elements only)
#pragma unroll
        for (int kk = 0; kk < 8; ++kk) { float v = Xrow[j0 + kk]; Xrow[j0 + kk] = 1.f - v * v; }
#pragma unroll
        for (int kk = 0; kk < 8; ++kk) { float v = Yrow[j0 + kk]; Yrow[j0 + kk] = 1.f - v * v; }
    }
    __syncthreads();

    // ---- h-net forward + input gradient ----
    // P8: h L1 -> Z, input zp = (q0,q1,q2,p0,p1)
    {
        float in5[5] = {q0, q1, q2, sm[r][SP0], sm[r][SP1]};
        mvK_fwd<5>(hW1, in5, j0, [&](int jj, float a) {
            Zrow[j0 + jj] = tanh_fast(a + hb1[j0 + jj]);
        });
    }
    __syncthreads();
    // P9: h L2 -> U = t = (1-h2^2) * hW3
    mv128_fwd(hW2, Zrow, j0, [&](int jj, float a) {
        float h = tanh_fast(a + hb2[j0 + jj]);
        Urow[j0 + jj] = (1.f - h * h) * hW3[j0 + jj];
    });
    __syncthreads();
    // P10: backward through L2: Z <- s = (1-h1^2) * (hW2 @ t)   (own-element in-place)
    mv128_bwd(hW2, Urow, j0, [&](int jj, float a) {
        float z = Zrow[j0 + jj];
        Zrow[j0 + jj] = (1.f - z * z) * a;
    });
    // (no barrier needed: P11 reads only own Z elements)
    // P11: dH_i = sum_j hW1[i][j] * s_j ; per-row scalar glue
    {
        float d[5] = {0.f, 0.f, 0.f, 0.f, 0.f};
#pragma unroll
        for (int kk = 0; kk < 8; ++kk) {
            float s = Zrow[j0 + kk];
#pragma unroll
            for (int i = 0; i < 5; ++i) d[i] += s * hW1[(size_t)i * 128 + j0 + kk];
        }
#pragma unroll
        for (int i = 0; i < 5; ++i) d[i] = red16(d[i]);
        if (jg == 0) {
            float F0 = sm[r][SF0], F1 = sm[r][SF1];
            float dHdq = -q2 * d[1] + q1 * d[2];
            sm[r][SDP0] = -d[0] + F0;
            sm[r][SDP1] = -dHdq + F1;
            sm[r][SV0] = d[3];
            sm[r][SV1] = -q2 * d[4];
            sm[r][SV2] = q1 * d[4];
        }
    }
    __syncthreads();

    // ---- m-net JVP with tangent v = dq3dt ----
    // P12: u1 = (v @ mW1) * c1  -> Z
    {
        float in3[3] = {sm[r][SV0], sm[r][SV1], sm[r][SV2]};
        mvK_fwd<3>(mW1, in3, j0, [&](int jj, float a) {
            Zrow[j0 + jj] = a * Xrow[j0 + jj];
        });
    }
    __syncthreads();
    // P13: u2 = (u1 @ mW2) * c2 -> U
    mv128_fwd(mW2, Zrow, j0, [&](int jj, float a) {
        Urow[j0 + jj] = a * Yrow[j0 + jj];
    });
    // (no barrier: P14 reads only own U elements)
    // P14: do = u2 @ mW3 ; dM = dA A^T + A dA^T ; ddq ; write outtile
    {
        float c[4] = {0.f, 0.f, 0.f, 0.f};
#pragma unroll
        for (int kk = 0; kk < 8; ++kk) {
            float v = Urow[j0 + kk];
            const float4 w = *(const float4*)(mW3 + (size_t)(j0 + kk) * 4);
            c[0] += v * w.x; c[1] += v * w.y; c[2] += v * w.z; c[3] += v * w.w;
        }
#pragma unroll
        for (int cc = 0; cc < 4; ++cc) c[cc] = red16(c[cc]);
        if (jg == 0) {
            float o0 = sm[r][SO0], o1 = sm[r][SO1], o2 = sm[r][SO2], o3 = sm[r][SO3];
            float do0 = c[0], do1 = c[1], do2 = c[2], do3 = c[3];
            float dM00 = 2.f * (do0 * o0 + do1 * o1);
            float dM11 = 2.f * (do2 * o2 + do3 * o3);
            float dM01 = do0 * o2 + do1 * o3 + o0 * do2 + o1 * do3;
            float M00 = sm[r][SM00], M01 = sm[r][SM01], M11 = sm[r][SM11];
            float p0 = sm[r][SP0], p1 = sm[r][SP1];
            float dp0 = sm[r][SDP0], dp1 = sm[r][SDP1];
            float ddq0 = M00 * dp0 + M01 * dp1 + dM00 * p0 + dM01 * p1;
            float ddq1 = M01 * dp0 + M11 * dp1 + dM01 * p0 + dM11 * p1;
            outtile[r * 6 + 0] = sm[r][SV0];
            outtile[r * 6 + 1] = sm[r][SV1];
            outtile[r * 6 + 2] = sm[r][SV2];
            outtile[r * 6 + 3] = ddq0;
            outtile[r * 6 + 4] = ddq1;
            outtile[r * 6 + 5] = 0.f;
        }
    }
    __syncthreads();
    // P15: cooperative coalesced store
    if (tid < T * 6) out[(size_t)rowbase * 6 + tid] = outtile[tid];
}

extern "C" void kernel_launch(void* const* d_in, const int* in_sizes, int n_in,
                              void* d_out, int out_size, void* d_ws, size_t ws_size,
                              hipStream_t stream) {
    (void)n_in; (void)d_ws; (void)ws_size; (void)out_size;
    // input order: 0:t 1:y 2..7:h_{W1,b1,W2,b2,W3,b3} 8..13:m_* 14..19:g_*
    const float* y   = (const float*)d_in[1];
    const float* hW1 = (const float*)d_in[2];
    const float* hb1 = (const float*)d_in[3];
    const float* hW2 = (const float*)d_in[4];
    const float* hb2 = (const float*)d_in[5];
    const float* hW3 = (const float*)d_in[6];
    const float* mW1 = (const float*)d_in[8];
    const float* mb1 = (const float*)d_in[9];
    const float* mW2 = (const float*)d_in[10];
    const float* mb2 = (const float*)d_in[11];
    const float* mW3 = (const float*)d_in[12];
    const float* mb3 = (const float*)d_in[13];
    const float* gW1 = (const float*)d_in[14];
    const float* gb1 = (const float*)d_in[15];
    const float* gW2 = (const float*)d_in[16];
    const float* gb2 = (const float*)d_in[17];
    const float* gW3 = (const float*)d_in[18];
    const float* gb3 = (const float*)d_in[19];
    float* out = (float*)d_out;

    int nrows = in_sizes[1] / 6;          // 131072
    dim3 grid(nrows / T), block(NTH);     // 4096 x 512
    symoden_kernel<<<grid, block, 0, stream>>>(y, hW1, hb1, hW2, hb2, hW3,
                                               mW1, mb1, mW2, mb2, mW3, mb3,
                                               gW1, gb1, gW2, gb2, gW3, gb3, out);
}